// Round 12
// baseline (113.156 us; speedup 1.0000x reference)
//
#include <hip/hip_runtime.h>
#include <hip/hip_bf16.h>

#define BATCH 16
#define SEQ 2048
#define DIM 64

typedef __attribute__((ext_vector_type(8))) __bf16 bf16x8;
typedef __attribute__((ext_vector_type(8))) unsigned short u16x8;
typedef __attribute__((ext_vector_type(4))) unsigned int u32x4;
typedef __attribute__((ext_vector_type(16))) float f32x16;

#if __has_builtin(__builtin_amdgcn_exp2f)
#define EXP2F(x) __builtin_amdgcn_exp2f(x)
#else
#define EXP2F(x) __expf(0.69314718055994531f * (x))
#endif

__device__ __forceinline__ unsigned short f2bf_hw(float f) {
    __bf16 h = (__bf16)f;
    return __builtin_bit_cast(unsigned short, h);
}

__device__ __forceinline__ unsigned int pk_bf16(float lo, float hi) {
    unsigned int a = f2bf_hw(lo), b = f2bf_hw(hi);
    return a | (b << 16);
}

__device__ __forceinline__ bf16x8 ld_bf8_g(const unsigned short* p) {
    u16x8 u = *(const u16x8*)p;
    return __builtin_bit_cast(bf16x8, u);
}

// Preconvert K and V to bf16 in fragment-order tile layout. 512 blocks:
// [0,256) = K path, [256,512) = V path (LDS-free transpose; lane d spans the
// wave so each j-column read is a coalesced 256B transaction).
//
// KEY PERMUTATION (kills the in-loop shuffle): K slot s within each 32-key
// subtile stores physical key with bits 2<->3 of (s&31) swapped. With that
// ordering, the S^T C-registers [8*c2 .. 8*c2+7] ARE the PV B-fragment for
// 16-key chunk c2 in register order, both lane-halves — no cross-lane swap.
// V stays in natural key order. Softmax sum + PV are key-permutation
// invariant as long as P and V agree (they now do by construction).
// K tile (b,t): [g 8][slot 128][8 shorts], element = K[b][t*128+phi(slot)][(g>>1)*16+(g&1)*8+j]
// V tile (b,t): [g 16][d 64][8 shorts],   element = V[b][t*128+(g>>1)*16+(g&1)*8+j][d]
__global__ __launch_bounds__(256)
void preconvert_kv(const float* __restrict__ K, const float* __restrict__ V,
                   unsigned short* __restrict__ Ks, unsigned short* __restrict__ Vts) {
    const int tid = threadIdx.x;
    if (blockIdx.x < 256) {
        const int b = blockIdx.x >> 4;
        const int t = blockIdx.x & 15;
        const float* src = K + ((size_t)(b * SEQ + t * 128)) * DIM;
        unsigned short* dst = Ks + ((size_t)(b * 16 + t)) * 8192;
        #pragma unroll
        for (int p = 0; p < 4; ++p) {
            const int cid = p * 256 + tid;          // cid = slot*8 + g
            const int slot = cid >> 3, g = cid & 7;
            // phi: swap bits 2 and 3 of the subtile-local key index
            const int s32 = slot & 31;
            const int skey = (slot & ~31) | (s32 & ~12) | (((s32 >> 2) & 1) << 3) | (((s32 >> 3) & 1) << 2);
            const int d0 = (g >> 1) * 16 + (g & 1) * 8;
            float4 x0 = *(const float4*)(src + skey * DIM + d0);
            float4 x1 = *(const float4*)(src + skey * DIM + d0 + 4);
            u16x8 o;
            o[0] = f2bf_hw(x0.x); o[1] = f2bf_hw(x0.y); o[2] = f2bf_hw(x0.z); o[3] = f2bf_hw(x0.w);
            o[4] = f2bf_hw(x1.x); o[5] = f2bf_hw(x1.y); o[6] = f2bf_hw(x1.z); o[7] = f2bf_hw(x1.w);
            *(u16x8*)(dst + (g * 128 + slot) * 8) = o;
        }
    } else {
        const int vb = blockIdx.x - 256;
        const int b = vb >> 4;
        const int t = vb & 15;
        const float* src = V + ((size_t)(b * SEQ + t * 128)) * DIM;
        unsigned short* dst = Vts + ((size_t)(b * 16 + t)) * 8192;
        #pragma unroll
        for (int p = 0; p < 4; ++p) {
            const int cid = p * 256 + tid;          // cid = g*64 + d
            const int g = cid >> 6, d = cid & 63;   // wave: g fixed, d = lane
            const int k0 = (g >> 1) * 16 + (g & 1) * 8;
            u16x8 o;
            #pragma unroll
            for (int j = 0; j < 8; ++j) o[j] = f2bf_hw(src[(k0 + j) * DIM + d]);
            *(u16x8*)(dst + (g * 64 + d) * 8) = o;
        }
    }
}

// Main: no LDS staging, no main-loop barriers, NO main-loop cross-lane ops.
// Block = 64 q-rows (2 q-sets per wave), 4 waves = 4 key-quarters (split-K;
// linear softmax -> partials add). K and V fragments register-prefetched one
// subtile ahead (waits land at the end-of-iteration copies, ~full pipeline of
// cover). P chain per subtile is now just exp2 -> pk -> MFMA.
__global__ __launch_bounds__(256, 2)
void attn_flash_kernel(const float* __restrict__ Q,
                       const unsigned short* __restrict__ Ks,
                       const unsigned short* __restrict__ Vts,
                       const float* __restrict__ scaling,
                       float* __restrict__ O) {
    __shared__ float comb[3 * 64 * 66];   // 50,688 B

    const int tid  = threadIdx.x;
    const int w    = tid >> 6;      // key-quarter 0..3
    const int lane = tid & 63;
    const int m    = lane & 31;     // q-index within frags
    const int h    = lane >> 5;     // k-half selector

    // XCD-aware swizzle: 2 batches per XCD -> ~1 MB KV working set per 4 MB L2
    const int x  = blockIdx.x;
    const int b  = ((x & 7) << 1) | ((x >> 3) & 1);
    const int q0 = (x >> 4) * 64;

    const float csc = 1.4426950408889634f / scaling[0];  // log2(e)/sqrt(D)

    // Q fragments for both q-sets, B-layout: lane (m,h) holds Q[q][c*16+h*8+{0..7}]*csc
    bf16x8 aq0[4], aq1[4];
    #pragma unroll
    for (int s = 0; s < 2; ++s) {
        const float* qsrc = Q + ((size_t)(b * SEQ + q0 + s * 32 + m)) * DIM + h * 8;
        #pragma unroll
        for (int c = 0; c < 4; ++c) {
            float4 x0 = *(const float4*)(qsrc + c * 16);
            float4 x1 = *(const float4*)(qsrc + c * 16 + 4);
            u32x4 pk;
            pk[0] = pk_bf16(x0.x * csc, x0.y * csc);
            pk[1] = pk_bf16(x0.z * csc, x0.w * csc);
            pk[2] = pk_bf16(x1.x * csc, x1.y * csc);
            pk[3] = pk_bf16(x1.z * csc, x1.w * csc);
            (s ? aq1 : aq0)[c] = __builtin_bit_cast(bf16x8, pk);
        }
    }

    f32x16 Oacc0[2], Oacc1[2];
    #pragma unroll
    for (int dt = 0; dt < 2; ++dt)
        #pragma unroll
        for (int r = 0; r < 16; ++r) { Oacc0[dt][r] = 0.f; Oacc1[dt][r] = 0.f; }
    float psum0 = 0.f, psum1 = 0.f;

    const unsigned short* Kbase = Ks + ((size_t)(b * 16 + w * 4)) * 8192;
    const unsigned short* Vbase = Vts + ((size_t)(b * 16 + w * 4)) * 8192;

    // prologue: K and V fragments for subtile 0
    bf16x8 kc[4], bv[2][2];
    #pragma unroll
    for (int c = 0; c < 4; ++c)
        kc[c] = ld_bf8_g(&Kbase[((c * 2 + h) * 128 + m) * 8]);
    #pragma unroll
    for (int c2 = 0; c2 < 2; ++c2)
        #pragma unroll
        for (int dt = 0; dt < 2; ++dt)
            bv[c2][dt] = ld_bf8_g(&Vbase[((c2 * 2 + h) * 64 + dt * 32 + m) * 8]);

    #pragma unroll 1
    for (int st = 0; st < 16; ++st) {
        // S^T = K Q^T for both q-sets (kc prefetched last iteration)
        f32x16 S0, S1;
        #pragma unroll
        for (int r = 0; r < 16; ++r) { S0[r] = 0.f; S1[r] = 0.f; }
        #pragma unroll
        for (int c = 0; c < 4; ++c) {
            S0 = __builtin_amdgcn_mfma_f32_32x32x16_bf16(kc[c], aq0[c], S0, 0, 0, 0);
            S1 = __builtin_amdgcn_mfma_f32_32x32x16_bf16(kc[c], aq1[c], S1, 0, 0, 0);
        }

        // prefetch next subtile's K AND V fragments (waits land at the copies below)
        const int stn = (st < 15) ? st + 1 : 15;
        const unsigned short* Ktn = Kbase + (size_t)(stn >> 2) * 8192;
        const unsigned short* Vtn = Vbase + (size_t)(stn >> 2) * 8192;
        const int tn = stn & 3;
        bf16x8 kn[4], vn[2][2];
        #pragma unroll
        for (int c = 0; c < 4; ++c)
            kn[c] = ld_bf8_g(&Ktn[((c * 2 + h) * 128 + tn * 32 + m) * 8]);
        #pragma unroll
        for (int c2 = 0; c2 < 2; ++c2)
            #pragma unroll
            for (int dt = 0; dt < 2; ++dt)
                vn[c2][dt] = ld_bf8_g(&Vtn[(((2 * tn + c2) * 2 + h) * 64 + dt * 32 + m) * 8]);

        // P = exp2(S); consecutive C-regs pack straight into the PV B-fragment
        // (key bit2<->3 permutation in the K pre-tiling makes this an identity)
        #pragma unroll
        for (int c2 = 0; c2 < 2; ++c2) {
            u32x4 pw0, pw1;
            #pragma unroll
            for (int i = 0; i < 4; ++i) {
                float a0 = EXP2F(S0[8 * c2 + 2 * i + 0]);
                float a1 = EXP2F(S0[8 * c2 + 2 * i + 1]);
                psum0 += a0 + a1;
                pw0[i] = pk_bf16(a0, a1);
                float b0 = EXP2F(S1[8 * c2 + 2 * i + 0]);
                float b1 = EXP2F(S1[8 * c2 + 2 * i + 1]);
                psum1 += b0 + b1;
                pw1[i] = pk_bf16(b0, b1);
            }
            bf16x8 pb0 = __builtin_bit_cast(bf16x8, pw0);
            bf16x8 pb1 = __builtin_bit_cast(bf16x8, pw1);
            #pragma unroll
            for (int dt = 0; dt < 2; ++dt) {
                Oacc0[dt] = __builtin_amdgcn_mfma_f32_32x32x16_bf16(bv[c2][dt], pb0, Oacc0[dt], 0, 0, 0);
                Oacc1[dt] = __builtin_amdgcn_mfma_f32_32x32x16_bf16(bv[c2][dt], pb1, Oacc1[dt], 0, 0, 0);
            }
        }

        #pragma unroll
        for (int c = 0; c < 4; ++c) kc[c] = kn[c];
        #pragma unroll
        for (int c2 = 0; c2 < 2; ++c2)
            #pragma unroll
            for (int dt = 0; dt < 2; ++dt) bv[c2][dt] = vn[c2][dt];
    }

    // combine 4 key-quarters through LDS, normalize, store (2 q-sets)
    float l0 = psum0 + __shfl_xor(psum0, 32);
    float l1 = psum1 + __shfl_xor(psum1, 32);
    if (w > 0) {
        float* dst = comb + ((w - 1) * 64 + lane) * 66;
        #pragma unroll
        for (int dt = 0; dt < 2; ++dt)
            #pragma unroll
            for (int r = 0; r < 16; ++r) {
                dst[dt * 16 + r]      = Oacc0[dt][r];
                dst[33 + dt * 16 + r] = Oacc1[dt][r];
            }
        dst[32] = l0;
        dst[65] = l1;
    }
    __syncthreads();
    if (w == 0) {
        const float* p0 = comb + (0 * 64 + lane) * 66;
        const float* p1 = comb + (1 * 64 + lane) * 66;
        const float* p2 = comb + (2 * 64 + lane) * 66;
        const float invl0 = 1.0f / (l0 + p0[32] + p1[32] + p2[32]);
        const float invl1 = 1.0f / (l1 + p0[65] + p1[65] + p2[65]);
        float* orow0 = O + ((size_t)(b * SEQ + q0 + m)) * DIM;
        float* orow1 = O + ((size_t)(b * SEQ + q0 + 32 + m)) * DIM;
        #pragma unroll
        for (int dt = 0; dt < 2; ++dt) {
            #pragma unroll
            for (int k = 0; k < 4; ++k) {
                float4 o4;
                #pragma unroll
                for (int j = 0; j < 4; ++j) {
                    const int r = 4 * k + j;
                    ((float*)&o4)[j] = (Oacc0[dt][r] + p0[dt * 16 + r] + p1[dt * 16 + r]
                                        + p2[dt * 16 + r]) * invl0;
                }
                *(float4*)(orow0 + dt * 32 + 8 * k + 4 * h) = o4;
                #pragma unroll
                for (int j = 0; j < 4; ++j) {
                    const int r = 4 * k + j;
                    ((float*)&o4)[j] = (Oacc1[dt][r] + p0[33 + dt * 16 + r] + p1[33 + dt * 16 + r]
                                        + p2[33 + dt * 16 + r]) * invl1;
                }
                *(float4*)(orow1 + dt * 32 + 8 * k + 4 * h) = o4;
            }
        }
    }
}

extern "C" void kernel_launch(void* const* d_in, const int* in_sizes, int n_in,
                              void* d_out, int out_size, void* d_ws, size_t ws_size,
                              hipStream_t stream) {
    const float* Q = (const float*)d_in[0];
    const float* K = (const float*)d_in[1];
    const float* V = (const float*)d_in[2];
    const float* scaling = (const float*)d_in[3];
    float* O = (float*)d_out;

    unsigned short* Ks  = (unsigned short*)d_ws;                  // 4 MB
    unsigned short* Vts = Ks + (size_t)BATCH * 16 * 8192;         // 4 MB

    preconvert_kv<<<dim3(512), dim3(256), 0, stream>>>(K, V, Ks, Vts);
    attn_flash_kernel<<<dim3(BATCH * (SEQ / 64)), dim3(256), 0, stream>>>(Q, Ks, Vts, scaling, O);
}

// Round 13
// 104.581 us; speedup vs baseline: 1.0820x; 1.0820x over previous
//
#include <hip/hip_runtime.h>
#include <hip/hip_bf16.h>

#define BATCH 16
#define SEQ 2048
#define DIM 64

typedef __attribute__((ext_vector_type(8))) __bf16 bf16x8;
typedef __attribute__((ext_vector_type(8))) unsigned short u16x8;
typedef __attribute__((ext_vector_type(4))) unsigned int u32x4;
typedef __attribute__((ext_vector_type(16))) float f32x16;

#if __has_builtin(__builtin_amdgcn_exp2f)
#define EXP2F(x) __builtin_amdgcn_exp2f(x)
#else
#define EXP2F(x) __expf(0.69314718055994531f * (x))
#endif

__device__ __forceinline__ unsigned short f2bf_hw(float f) {
    __bf16 h = (__bf16)f;
    return __builtin_bit_cast(unsigned short, h);
}

__device__ __forceinline__ unsigned int pk_bf16(float lo, float hi) {
    unsigned int a = f2bf_hw(lo), b = f2bf_hw(hi);
    return a | (b << 16);
}

__device__ __forceinline__ bf16x8 ld_bf8_g(const unsigned short* p) {
    u16x8 u = *(const u16x8*)p;
    return __builtin_bit_cast(bf16x8, u);
}

// Preconvert K and V to bf16 in fragment-order tile layout. 512 blocks:
// [0,256) = K path, [256,512) = V path (LDS-free transpose; lane d spans the
// wave so each j-column read is a coalesced 256B transaction).
// K slot s within each 32-key subtile stores the physical key with bits 2<->3
// of (s&31) swapped: then S^T C-registers [8c2..8c2+7] ARE the PV B-fragment
// in register order (no cross-lane swap). V stays natural; softmax sum and PV
// are key-permutation invariant since P and V agree.
__global__ __launch_bounds__(256)
void preconvert_kv(const float* __restrict__ K, const float* __restrict__ V,
                   unsigned short* __restrict__ Ks, unsigned short* __restrict__ Vts) {
    const int tid = threadIdx.x;
    if (blockIdx.x < 256) {
        const int b = blockIdx.x >> 4;
        const int t = blockIdx.x & 15;
        const float* src = K + ((size_t)(b * SEQ + t * 128)) * DIM;
        unsigned short* dst = Ks + ((size_t)(b * 16 + t)) * 8192;
        #pragma unroll
        for (int p = 0; p < 4; ++p) {
            const int cid = p * 256 + tid;          // cid = slot*8 + g
            const int slot = cid >> 3, g = cid & 7;
            const int s32 = slot & 31;
            const int skey = (slot & ~31) | (s32 & ~12) | (((s32 >> 2) & 1) << 3) | (((s32 >> 3) & 1) << 2);
            const int d0 = (g >> 1) * 16 + (g & 1) * 8;
            float4 x0 = *(const float4*)(src + skey * DIM + d0);
            float4 x1 = *(const float4*)(src + skey * DIM + d0 + 4);
            u16x8 o;
            o[0] = f2bf_hw(x0.x); o[1] = f2bf_hw(x0.y); o[2] = f2bf_hw(x0.z); o[3] = f2bf_hw(x0.w);
            o[4] = f2bf_hw(x1.x); o[5] = f2bf_hw(x1.y); o[6] = f2bf_hw(x1.z); o[7] = f2bf_hw(x1.w);
            *(u16x8*)(dst + (g * 128 + slot) * 8) = o;
        }
    } else {
        const int vb = blockIdx.x - 256;
        const int b = vb >> 4;
        const int t = vb & 15;
        const float* src = V + ((size_t)(b * SEQ + t * 128)) * DIM;
        unsigned short* dst = Vts + ((size_t)(b * 16 + t)) * 8192;
        #pragma unroll
        for (int p = 0; p < 4; ++p) {
            const int cid = p * 256 + tid;          // cid = g*64 + d
            const int g = cid >> 6, d = cid & 63;   // wave: g fixed, d = lane
            const int k0 = (g >> 1) * 16 + (g & 1) * 8;
            u16x8 o;
            #pragma unroll
            for (int j = 0; j < 8; ++j) o[j] = f2bf_hw(src[(k0 + j) * DIM + d]);
            *(u16x8*)(dst + (g * 64 + d) * 8) = o;
        }
    }
}

// Main: no LDS staging, no main-loop barriers, no main-loop cross-lane ops.
// Block = 64 q-rows (2 q-sets/wave), 4 waves = 4 key-quarters (split-K).
// DOUBLE-BUFFERED register pipeline: kb/vb[2] ping-pong; iter N consumes
// buffer N&1 then reloads it in place for iter N+2 (WAR-safe: MFMA already
// read the regs). Loads get ~2 iterations (~1200 cyc) of cover and there are
// no end-of-iteration copies. unroll 2 makes the buffer index compile-time.
__global__ __launch_bounds__(256, 2)
void attn_flash_kernel(const float* __restrict__ Q,
                       const unsigned short* __restrict__ Ks,
                       const unsigned short* __restrict__ Vts,
                       const float* __restrict__ scaling,
                       float* __restrict__ O) {
    __shared__ float comb[3 * 64 * 66];   // 50,688 B

    const int tid  = threadIdx.x;
    const int w    = tid >> 6;      // key-quarter 0..3
    const int lane = tid & 63;
    const int m    = lane & 31;     // q-index within frags
    const int h    = lane >> 5;     // k-half selector

    // XCD-aware swizzle: 2 batches per XCD -> ~1 MB KV working set per 4 MB L2
    const int x  = blockIdx.x;
    const int b  = ((x & 7) << 1) | ((x >> 3) & 1);
    const int q0 = (x >> 4) * 64;

    const float csc = 1.4426950408889634f / scaling[0];  // log2(e)/sqrt(D)

    // Q fragments for both q-sets, B-layout
    bf16x8 aq0[4], aq1[4];
    #pragma unroll
    for (int s = 0; s < 2; ++s) {
        const float* qsrc = Q + ((size_t)(b * SEQ + q0 + s * 32 + m)) * DIM + h * 8;
        #pragma unroll
        for (int c = 0; c < 4; ++c) {
            float4 x0 = *(const float4*)(qsrc + c * 16);
            float4 x1 = *(const float4*)(qsrc + c * 16 + 4);
            u32x4 pk;
            pk[0] = pk_bf16(x0.x * csc, x0.y * csc);
            pk[1] = pk_bf16(x0.z * csc, x0.w * csc);
            pk[2] = pk_bf16(x1.x * csc, x1.y * csc);
            pk[3] = pk_bf16(x1.z * csc, x1.w * csc);
            (s ? aq1 : aq0)[c] = __builtin_bit_cast(bf16x8, pk);
        }
    }

    f32x16 Oacc0[2], Oacc1[2];
    #pragma unroll
    for (int dt = 0; dt < 2; ++dt)
        #pragma unroll
        for (int r = 0; r < 16; ++r) { Oacc0[dt][r] = 0.f; Oacc1[dt][r] = 0.f; }
    float psum0 = 0.f, psum1 = 0.f;

    const unsigned short* Kbase = Ks + ((size_t)(b * 16 + w * 4)) * 8192;
    const unsigned short* Vbase = Vts + ((size_t)(b * 16 + w * 4)) * 8192;

    // prologue: fill both buffers (subtiles 0 and 1; both in it=0 -> tile 0)
    bf16x8 kb[2][4], vb[2][2][2];
    #pragma unroll
    for (int s = 0; s < 2; ++s) {
        #pragma unroll
        for (int c = 0; c < 4; ++c)
            kb[s][c] = ld_bf8_g(&Kbase[((c * 2 + h) * 128 + s * 32 + m) * 8]);
        #pragma unroll
        for (int c2 = 0; c2 < 2; ++c2)
            #pragma unroll
            for (int dt = 0; dt < 2; ++dt)
                vb[s][c2][dt] = ld_bf8_g(&Vbase[(((2 * s + c2) * 2 + h) * 64 + dt * 32 + m) * 8]);
    }

    #pragma unroll 2
    for (int st = 0; st < 16; ++st) {
        const int p = st & 1;   // compile-time under unroll 2

        // S^T = K Q^T for both q-sets
        f32x16 S0, S1;
        #pragma unroll
        for (int r = 0; r < 16; ++r) { S0[r] = 0.f; S1[r] = 0.f; }
        #pragma unroll
        for (int c = 0; c < 4; ++c) {
            S0 = __builtin_amdgcn_mfma_f32_32x32x16_bf16(kb[p][c], aq0[c], S0, 0, 0, 0);
            S1 = __builtin_amdgcn_mfma_f32_32x32x16_bf16(kb[p][c], aq1[c], S1, 0, 0, 0);
        }

        // reload kb[p] in place for subtile st+2 (consumed two iterations later)
        const int stn = (st + 2 < 16) ? st + 2 : 15;   // tail clamp (redundant loads)
        {
            const unsigned short* Ktn = Kbase + (size_t)(stn >> 2) * 8192;
            const int tn = stn & 3;
            #pragma unroll
            for (int c = 0; c < 4; ++c)
                kb[p][c] = ld_bf8_g(&Ktn[((c * 2 + h) * 128 + tn * 32 + m) * 8]);
        }

        // P = exp2(S); consecutive C-regs pack straight into the PV B-fragment
        #pragma unroll
        for (int c2 = 0; c2 < 2; ++c2) {
            u32x4 pw0, pw1;
            #pragma unroll
            for (int i = 0; i < 4; ++i) {
                float a0 = EXP2F(S0[8 * c2 + 2 * i + 0]);
                float a1 = EXP2F(S0[8 * c2 + 2 * i + 1]);
                psum0 += a0 + a1;
                pw0[i] = pk_bf16(a0, a1);
                float b0 = EXP2F(S1[8 * c2 + 2 * i + 0]);
                float b1 = EXP2F(S1[8 * c2 + 2 * i + 1]);
                psum1 += b0 + b1;
                pw1[i] = pk_bf16(b0, b1);
            }
            bf16x8 pb0 = __builtin_bit_cast(bf16x8, pw0);
            bf16x8 pb1 = __builtin_bit_cast(bf16x8, pw1);
            #pragma unroll
            for (int dt = 0; dt < 2; ++dt) {
                Oacc0[dt] = __builtin_amdgcn_mfma_f32_32x32x16_bf16(vb[p][c2][dt], pb0, Oacc0[dt], 0, 0, 0);
                Oacc1[dt] = __builtin_amdgcn_mfma_f32_32x32x16_bf16(vb[p][c2][dt], pb1, Oacc1[dt], 0, 0, 0);
            }
        }

        // reload vb[p] in place for subtile st+2
        {
            const unsigned short* Vtn = Vbase + (size_t)(stn >> 2) * 8192;
            const int tn = stn & 3;
            #pragma unroll
            for (int c2 = 0; c2 < 2; ++c2)
                #pragma unroll
                for (int dt = 0; dt < 2; ++dt)
                    vb[p][c2][dt] = ld_bf8_g(&Vtn[(((2 * tn + c2) * 2 + h) * 64 + dt * 32 + m) * 8]);
        }
    }

    // combine 4 key-quarters through LDS, normalize, store (2 q-sets)
    float l0 = psum0 + __shfl_xor(psum0, 32);
    float l1 = psum1 + __shfl_xor(psum1, 32);
    if (w > 0) {
        float* dst = comb + ((w - 1) * 64 + lane) * 66;
        #pragma unroll
        for (int dt = 0; dt < 2; ++dt)
            #pragma unroll
            for (int r = 0; r < 16; ++r) {
                dst[dt * 16 + r]      = Oacc0[dt][r];
                dst[33 + dt * 16 + r] = Oacc1[dt][r];
            }
        dst[32] = l0;
        dst[65] = l1;
    }
    __syncthreads();
    if (w == 0) {
        const float* p0 = comb + (0 * 64 + lane) * 66;
        const float* p1 = comb + (1 * 64 + lane) * 66;
        const float* p2 = comb + (2 * 64 + lane) * 66;
        const float invl0 = 1.0f / (l0 + p0[32] + p1[32] + p2[32]);
        const float invl1 = 1.0f / (l1 + p0[65] + p1[65] + p2[65]);
        float* orow0 = O + ((size_t)(b * SEQ + q0 + m)) * DIM;
        float* orow1 = O + ((size_t)(b * SEQ + q0 + 32 + m)) * DIM;
        #pragma unroll
        for (int dt = 0; dt < 2; ++dt) {
            #pragma unroll
            for (int k = 0; k < 4; ++k) {
                float4 o4;
                #pragma unroll
                for (int j = 0; j < 4; ++j) {
                    const int r = 4 * k + j;
                    ((float*)&o4)[j] = (Oacc0[dt][r] + p0[dt * 16 + r] + p1[dt * 16 + r]
                                        + p2[dt * 16 + r]) * invl0;
                }
                *(float4*)(orow0 + dt * 32 + 8 * k + 4 * h) = o4;
                #pragma unroll
                for (int j = 0; j < 4; ++j) {
                    const int r = 4 * k + j;
                    ((float*)&o4)[j] = (Oacc1[dt][r] + p0[33 + dt * 16 + r] + p1[33 + dt * 16 + r]
                                        + p2[33 + dt * 16 + r]) * invl1;
                }
                *(float4*)(orow1 + dt * 32 + 8 * k + 4 * h) = o4;
            }
        }
    }
}

extern "C" void kernel_launch(void* const* d_in, const int* in_sizes, int n_in,
                              void* d_out, int out_size, void* d_ws, size_t ws_size,
                              hipStream_t stream) {
    const float* Q = (const float*)d_in[0];
    const float* K = (const float*)d_in[1];
    const float* V = (const float*)d_in[2];
    const float* scaling = (const float*)d_in[3];
    float* O = (float*)d_out;

    unsigned short* Ks  = (unsigned short*)d_ws;                  // 4 MB
    unsigned short* Vts = Ks + (size_t)BATCH * 16 * 8192;         // 4 MB

    preconvert_kv<<<dim3(512), dim3(256), 0, stream>>>(K, V, Ks, Vts);
    attn_flash_kernel<<<dim3(BATCH * (SEQ / 64)), dim3(256), 0, stream>>>(Q, Ks, Vts, scaling, O);
}